// Round 15
// baseline (96.428 us; speedup 1.0000x reference)
//
#include <hip/hip_runtime.h>
#include <math.h>

// Problem constants
#define Mm 4096   // batch B
#define Nn 4096   // 4*H, column map: c = (h>>4)*64 + g*16 + (h&15)
#define Kk 2048   // D + H

typedef __bf16 bf16x8 __attribute__((ext_vector_type(8)));
typedef float f32x4 __attribute__((ext_vector_type(4)));

__device__ __forceinline__ unsigned short f2bf(float f) {
    union { float f; unsigned u; } v; v.f = f;
    unsigned r = v.u + 0x7FFFu + ((v.u >> 16) & 1u);  // RNE
    return (unsigned short)(r >> 16);
}

__device__ __forceinline__ float fast_tanh(float x) {
    return 1.f - 2.f / (1.f + __expf(2.f * x));
}

// ---------------------------------------------------------------------------
// Kernel 1: pack x|h -> Xcat bf16 [4096][2048]
//   W|U -> Wcat bf16 [4096][2048], row n' = (h>>4)*64 + g*16 + (h&15)
//   bsum[4h+g] = bW+bU.
// ---------------------------------------------------------------------------
__global__ void pack_bf16(const float* __restrict__ x, const float* __restrict__ h,
                          const float* __restrict__ W, const float* __restrict__ U,
                          const float* __restrict__ bW, const float* __restrict__ bU,
                          unsigned short* __restrict__ Xc, unsigned short* __restrict__ Wc,
                          float* __restrict__ bsum) {
    if (blockIdx.x == 0) {
#pragma unroll
        for (int j = 0; j < 16; ++j) {
            int n = threadIdx.x * 16 + j;
            int hh = n >> 2, g = n & 3;
            bsum[n] = bW[g * 1024 + hh] + bU[g * 1024 + hh];
        }
    }
    const int PER = (4096 * 1024) / 4;
    for (int t = blockIdx.x * blockDim.x + threadIdx.x; t < 4 * PER;
         t += gridDim.x * blockDim.x) {
        int region = t >> 20;
        int i = t & (PER - 1);
        int row = i >> 8;
        int c4  = i & 255;
        const float* src = (region == 0) ? x : (region == 1) ? h : (region == 2) ? W : U;
        float4 v = reinterpret_cast<const float4*>(src)[i];
        ushort4 o;
        o.x = f2bf(v.x); o.y = f2bf(v.y); o.z = f2bf(v.z); o.w = f2bf(v.w);
        if (region < 2) {
            *reinterpret_cast<ushort4*>(Xc + (size_t)row * 2048 + (region << 10) + c4 * 4) = o;
        } else {
            int g = row >> 10, hh = row & 1023;
            int np = ((hh >> 4) << 6) + (g << 4) + (hh & 15);
            *reinterpret_cast<ushort4*>(Wc + (size_t)np * 2048 + ((region & 1) << 10) + c4 * 4) = o;
        }
    }
}

// ---------------------------------------------------------------------------
// Kernel 2: 128x256 tile, BK=32, 3-buffer LDS (72 KiB -> 2 blocks/CU),
//           1 barrier + 1 vmcnt(3) per K-tile, register-only LSTM epilogue.
// LDS pack: row q of a buffer holds global rows {q, q+half} (128-B LDS rows)
// with the proven (q&7)<<4 XOR swizzle applied consistently on both sides.
// ---------------------------------------------------------------------------
__device__ __forceinline__ void gl16(const void* g, void* l) {
    __builtin_amdgcn_global_load_lds(
        (const __attribute__((address_space(1))) void*)g,
        (__attribute__((address_space(3))) void*)l, 16, 0, 0);
}

__global__ __launch_bounds__(512, 2) void gemm_occ(const unsigned short* __restrict__ A,
                                                   const unsigned short* __restrict__ Bw,
                                                   const float* __restrict__ bsum,
                                                   const float* __restrict__ cprev,
                                                   float* __restrict__ out) {
    extern __shared__ char lds[];
    const int tid = threadIdx.x, lane = tid & 63, wave = tid >> 6;
    const int wm = wave >> 2, wn = wave & 3;   // 2M x 4N waves, per-wave 64x64

    // bijective XCD swizzle: 512 wgs, 8 XCDs, 64 per chunk
    const int bid = blockIdx.x;
    const int swz = (bid & 7) * 64 + (bid >> 3);
    const int bm = swz & 31, bn = swz >> 5;    // 32 M-blocks x 16 N-blocks
    const size_t Crow0 = (size_t)bm * 128, Ccol0 = (size_t)bn * 256;

    // ---- staging source addresses (per-lane, inverse-swizzled row-pair pack)
    // A tile: 128 rows x 32 k -> LDS [64][128B]; thread t: q=t>>3, s=t&7,
    // s2=s^(q&7): rowoff=(s2>>2)*64, kbyte=(s2&3)*16.
    {
    }
    const int sq = tid >> 3, ss = tid & 7;
    const int s2a = ss ^ (sq & 7);
    const char* aSrc = (const char*)A +
        (size_t)(Crow0 + sq + ((s2a >> 2) * 64)) * 4096 + (s2a & 3) * 16;
    // B tile: 256 rows x 32 k -> LDS [128][128B]; two issues j=0/1, q=j*64+(t>>3)
    const int bq0 = sq, bq1 = 64 + sq;
    const int s2b0 = ss ^ (bq0 & 7), s2b1 = ss ^ (bq1 & 7);
    const char* bSrc0 = (const char*)Bw +
        (size_t)(Ccol0 + bq0 + ((s2b0 >> 2) * 128)) * 4096 + (s2b0 & 3) * 16;
    const char* bSrc1 = (const char*)Bw +
        (size_t)(Ccol0 + bq1 + ((s2b1 >> 2) * 128)) * 4096 + (s2b1 & 3) * 16;

    // buffer offsets: A bufs 0/8192/16384 ; B bufs 24576/40960/57344
#define STGA(off, ktb) gl16(aSrc + (ktb), lds + (off) + wave * 1024)
#define STGB(off, ktb) do { \
        gl16(bSrc0 + (ktb), lds + (off) + wave * 1024); \
        gl16(bSrc1 + (ktb), lds + (off) + 8192 + wave * 1024); } while (0)

    // ---- LDS read addressing
    // A frag (mf): row r = wm*64+mf*16+(lane&15); q = mf*16+(lane&15); half=wm
    // slot = (wm*4 + (lane>>4)) ^ (lane&7)  [q&7 == lane&7]
    const int aConst = (lane & 15) * 128 + (((wm * 4 + (lane >> 4)) ^ (lane & 7)) << 4);
    // B frag (nf): col c = wn*64+nf*16+(lane&15); q=(wn&1)*64+nf*16+(lane&15); half=wn>>1
    const int bConst = ((wn & 1) * 64 + (lane & 15)) * 128 +
                       ((((wn >> 1) * 4 + (lane >> 4)) ^ (lane & 7)) << 4);

#define LDAq(off, mf) (*(const bf16x8*)(lds + (off) + aConst + (mf) * 2048))
#define LDBq(off, nf) (*(const bf16x8*)(lds + (off) + bConst + (nf) * 2048))

    f32x4 acc[4][4] = {};  // [mf][nf], 64 VGPRs
    bf16x8 af0, af1, af2, af3, bf0, bf1, bf2, bf3;

#define MFMA(a, b, c) __builtin_amdgcn_mfma_f32_16x16x32_bf16(a, b, c, 0, 0, 0)
    // 16 independent MFMAs (each acc touched once per K-tile)
#define CL16 \
    acc[0][0] = MFMA(af0, bf0, acc[0][0]); \
    acc[1][0] = MFMA(af1, bf0, acc[1][0]); \
    acc[2][0] = MFMA(af2, bf0, acc[2][0]); \
    acc[3][0] = MFMA(af3, bf0, acc[3][0]); \
    acc[0][1] = MFMA(af0, bf1, acc[0][1]); \
    acc[1][1] = MFMA(af1, bf1, acc[1][1]); \
    acc[2][1] = MFMA(af2, bf1, acc[2][1]); \
    acc[3][1] = MFMA(af3, bf1, acc[3][1]); \
    acc[0][2] = MFMA(af0, bf2, acc[0][2]); \
    acc[1][2] = MFMA(af1, bf2, acc[1][2]); \
    acc[2][2] = MFMA(af2, bf2, acc[2][2]); \
    acc[3][2] = MFMA(af3, bf2, acc[3][2]); \
    acc[0][3] = MFMA(af0, bf3, acc[0][3]); \
    acc[1][3] = MFMA(af1, bf3, acc[1][3]); \
    acc[2][3] = MFMA(af2, bf3, acc[2][3]); \
    acc[3][3] = MFMA(af3, bf3, acc[3][3]);

    // ---- prologue: stage tiles 0,1; drain t0; read frags(0)
    STGA(0, 0);           STGB(24576, 0);
    STGA(8192, 64);       STGB(40960, 64);
    asm volatile("s_waitcnt vmcnt(3)" ::: "memory");
    __builtin_amdgcn_s_barrier();
    af0 = LDAq(0, 0); af1 = LDAq(0, 1); af2 = LDAq(0, 2); af3 = LDAq(0, 3);
    bf0 = LDBq(24576, 0); bf1 = LDBq(24576, 1); bf2 = LDBq(24576, 2); bf3 = LDBq(24576, 3);

    // rotating buffer offsets: read=(t+1)%3, stage=(t+2)%3, x=t%3
    int oAr = 8192, oAs = 16384, oAx = 0;
    int oBr = 40960, oBs = 57344, oBx = 24576;

    // ---- main loop: K-tiles 0..62 full body, tile 63 tail cluster
    for (int t = 0; t < 63; ++t) {
        const int kt2 = t + 2;
        const size_t ktb = (size_t)(kt2 <= 63 ? kt2 : 0) * 64;
        __builtin_amdgcn_s_setprio(1);
        CL16
        __builtin_amdgcn_s_setprio(0);
        STGA(oAs, ktb);
        STGB(oBs, ktb);
        asm volatile("s_waitcnt vmcnt(3)" ::: "memory");
        __builtin_amdgcn_s_barrier();
        af0 = LDAq(oAr, 0); af1 = LDAq(oAr, 1); af2 = LDAq(oAr, 2); af3 = LDAq(oAr, 3);
        bf0 = LDBq(oBr, 0); bf1 = LDBq(oBr, 1); bf2 = LDBq(oBr, 2); bf3 = LDBq(oBr, 3);
        int tA = oAx; oAx = oAr; oAr = oAs; oAs = tA;
        int tB = oBx; oBx = oBr; oBr = oBs; oBs = tB;
    }
    __builtin_amdgcn_s_setprio(1);
    CL16
    __builtin_amdgcn_s_setprio(0);

    // ---- register-only fused LSTM epilogue ---------------------------------
    const int hl = lane & 15;
    const int er0 = (lane >> 4) * 4;
    const int myh = (int)(Ccol0 >> 2) + wn * 16 + hl;
    const f32x4 bs = *(const f32x4*)(bsum + (size_t)myh * 4);

    float cp[4][4];
#pragma unroll
    for (int mf = 0; mf < 4; ++mf)
#pragma unroll
        for (int r = 0; r < 4; ++r)
            cp[mf][r] = cprev[(size_t)(Crow0 + wm * 64 + mf * 16 + er0 + r) * 1024 + myh];

#pragma unroll
    for (int mf = 0; mf < 4; ++mf)
#pragma unroll
        for (int r = 0; r < 4; ++r) {
            float gi = acc[mf][0][r] + bs[0];
            float gf = acc[mf][1][r] + bs[1];
            float go = acc[mf][2][r] + bs[2];
            float gz = acc[mf][3][r] + bs[3];
            float iv = 1.f / (1.f + __expf(-gi));
            float fv = 1.f / (1.f + __expf(-gf));
            float ov = 1.f / (1.f + __expf(-go));
            float zv = fast_tanh(gz);
            float cc = fmaf(iv, zv, fv * cp[mf][r]);
            float hv = ov * fast_tanh(cc);
            const size_t oidx =
                (size_t)(Crow0 + wm * 64 + mf * 16 + er0 + r) * 1024 + myh;
            out[oidx] = hv;
            out[(1 << 22) + oidx] = cc;
        }

    // drain outstanding dummy prefetches before LDS dealloc at endpgm
    asm volatile("s_waitcnt vmcnt(0)" ::: "memory");
}

// ---------------------------------------------------------------------------
extern "C" void kernel_launch(void* const* d_in, const int* in_sizes, int n_in,
                              void* d_out, int out_size, void* d_ws, size_t ws_size,
                              hipStream_t stream) {
    const float* x  = (const float*)d_in[0];
    const float* h  = (const float*)d_in[1];
    const float* c  = (const float*)d_in[2];
    const float* W  = (const float*)d_in[3];
    const float* bW = (const float*)d_in[4];
    const float* U  = (const float*)d_in[5];
    const float* bU = (const float*)d_in[6];
    float* out = (float*)d_out;

    char* ws = (char*)d_ws;
    unsigned short* Xc = (unsigned short*)ws;                         // 16 MB
    unsigned short* Wc = (unsigned short*)(ws + ((size_t)16 << 20));  // 16 MB
    float* bsum = (float*)(ws + ((size_t)32 << 20));                  // 16 KB

    (void)hipFuncSetAttribute((const void*)gemm_occ,
                              hipFuncAttributeMaxDynamicSharedMemorySize, 73728);

    hipLaunchKernelGGL(pack_bf16, dim3(2048), dim3(256), 0, stream,
                       x, h, W, U, bW, bU, Xc, Wc, bsum);
    hipLaunchKernelGGL(gemm_occ, dim3(512), dim3(512), 73728, stream,
                       Xc, Wc, bsum, c, out);
}

// Round 16
// 82.957 us; speedup vs baseline: 1.1624x; 1.1624x over previous
//
#include <hip/hip_runtime.h>
#include <math.h>

// Problem constants
#define Mm 4096   // batch B
#define Nn 4096   // 4*H, column map: c = (h>>4)*64 + g*16 + (h&15)
#define Kk 2048   // D + H

typedef __bf16 bf16x8 __attribute__((ext_vector_type(8)));
typedef float f32x4 __attribute__((ext_vector_type(4)));

__device__ __forceinline__ unsigned short f2bf(float f) {
    union { float f; unsigned u; } v; v.f = f;
    unsigned r = v.u + 0x7FFFu + ((v.u >> 16) & 1u);  // RNE
    return (unsigned short)(r >> 16);
}

__device__ __forceinline__ float fast_tanh(float x) {
    return 1.f - 2.f / (1.f + __expf(2.f * x));
}

// ---------------------------------------------------------------------------
// Kernel 1: pack x|h -> Xcat bf16 [4096][2048]
//   W|U -> Wcat bf16 [4096][2048], row n' = (h>>4)*64 + g*16 + (h&15)
//   bsum[4h+g] = bW+bU.
// ---------------------------------------------------------------------------
__global__ void pack_bf16(const float* __restrict__ x, const float* __restrict__ h,
                          const float* __restrict__ W, const float* __restrict__ U,
                          const float* __restrict__ bW, const float* __restrict__ bU,
                          unsigned short* __restrict__ Xc, unsigned short* __restrict__ Wc,
                          float* __restrict__ bsum) {
    if (blockIdx.x == 0) {
#pragma unroll
        for (int j = 0; j < 16; ++j) {
            int n = threadIdx.x * 16 + j;
            int hh = n >> 2, g = n & 3;
            bsum[n] = bW[g * 1024 + hh] + bU[g * 1024 + hh];
        }
    }
    const int PER = (4096 * 1024) / 4;
    for (int t = blockIdx.x * blockDim.x + threadIdx.x; t < 4 * PER;
         t += gridDim.x * blockDim.x) {
        int region = t >> 20;
        int i = t & (PER - 1);
        int row = i >> 8;
        int c4  = i & 255;
        const float* src = (region == 0) ? x : (region == 1) ? h : (region == 2) ? W : U;
        float4 v = reinterpret_cast<const float4*>(src)[i];
        ushort4 o;
        o.x = f2bf(v.x); o.y = f2bf(v.y); o.z = f2bf(v.z); o.w = f2bf(v.w);
        if (region < 2) {
            *reinterpret_cast<ushort4*>(Xc + (size_t)row * 2048 + (region << 10) + c4 * 4) = o;
        } else {
            int g = row >> 10, hh = row & 1023;
            int np = ((hh >> 4) << 6) + (g << 4) + (hh & 15);
            *reinterpret_cast<ushort4*>(Wc + (size_t)np * 2048 + ((region & 1) << 10) + c4 * 4) = o;
        }
    }
}

// ---------------------------------------------------------------------------
// Kernel 2: 256x256 GEMM, cross-phase pipelined A-quads (R12 schedule),
//           STG after cluster, guarded tail stages, register-only epilogue.
// ---------------------------------------------------------------------------
__device__ __forceinline__ void gl16(const void* g, void* l) {
    __builtin_amdgcn_global_load_lds(
        (const __attribute__((address_space(1))) void*)g,
        (__attribute__((address_space(3))) void*)l, 16, 0, 0);
}

#define A_OFF(p, ah) (((p) * 2 + (ah)) * 16384)
#define B_OFF(p, hb) (65536 + ((p) * 2 + (hb)) * 16384)

__global__ __launch_bounds__(512, 2) void gemm_8ph(const unsigned short* __restrict__ A,
                                                   const unsigned short* __restrict__ Bw,
                                                   const float* __restrict__ bsum,
                                                   const float* __restrict__ cprev,
                                                   float* __restrict__ out) {
    extern __shared__ char lds[];
    const int tid = threadIdx.x, lane = tid & 63, wave = tid >> 6;
    const int wm = wave >> 2, wn = wave & 3;

    const int bid = blockIdx.x;
    const int swz = (bid & 7) * 32 + (bid >> 3);
    const int bm = swz & 15, bn = swz >> 4;
    const size_t Crow0 = (size_t)bm * 256, Ccol0 = (size_t)bn * 256;

    // ---- staging source addresses (inverse-swizzled global, linear LDS dest)
    const int srow = wave * 8 + (lane >> 3);
    const int scolswz = (((lane & 7) ^ (lane >> 3)) << 4);
    const char* aS[2][2];
    const char* bS[2][2];
#pragma unroll
    for (int ah = 0; ah < 2; ++ah)
#pragma unroll
        for (int j = 0; j < 2; ++j) {
            aS[ah][j] = (const char*)A  + (size_t)(Crow0 + ah * 128 + j * 64 + srow) * 4096 + scolswz;
            bS[ah][j] = (const char*)Bw + (size_t)(Ccol0 + ah * 128 + j * 64 + srow) * 4096 + scolswz;
        }

#define STG_A(p, ah, kb) do { \
        gl16(aS[ah][0] + (kb), lds + A_OFF(p, ah) + wave * 1024); \
        gl16(aS[ah][1] + (kb), lds + A_OFF(p, ah) + 8192 + wave * 1024); } while (0)
#define STG_B(p, hb, kb) do { \
        gl16(bS[hb][0] + (kb), lds + B_OFF(p, hb) + wave * 1024); \
        gl16(bS[hb][1] + (kb), lds + B_OFF(p, hb) + 8192 + wave * 1024); } while (0)

    // ---- LDS read addressing (swizzled), 16x16x32 frags
    const int arowB = (wm * 64 + (lane & 15)) * 128;
    const int browB = ((wn & 1) * 64 + (lane & 15)) * 128;
    const int c0 = (((lane >> 4) << 4)) ^ ((lane & 7) << 4);
    const int c1 = (64 + ((lane >> 4) << 4)) ^ ((lane & 7) << 4);
    const int bhb = wn >> 1;

#define LDA(p, ah, mfl, ck) (*(const bf16x8*)(lds + A_OFF(p, ah) + arowB + (mfl) * 2048 + (ck)))
#define LDB(p, nf, ck)      (*(const bf16x8*)(lds + B_OFF(p, bhb) + browB + (nf) * 2048 + (ck)))

    f32x4 acc[2][4][4] = {};

#define MFMA(a, b, c) __builtin_amdgcn_mfma_f32_16x16x32_bf16(a, b, c, 0, 0, 0)
    // 16 MFMAs per cluster, acc reuse distance 8; per-acc order k0 then k1.
#define MF16(ah, mfA, mfB, p00, p01, p10, p11) \
    acc[ah][mfA][0] = MFMA(p00, b00, acc[ah][mfA][0]); \
    acc[ah][mfA][1] = MFMA(p00, b10, acc[ah][mfA][1]); \
    acc[ah][mfA][2] = MFMA(p00, b20, acc[ah][mfA][2]); \
    acc[ah][mfA][3] = MFMA(p00, b30, acc[ah][mfA][3]); \
    acc[ah][mfB][0] = MFMA(p10, b00, acc[ah][mfB][0]); \
    acc[ah][mfB][1] = MFMA(p10, b10, acc[ah][mfB][1]); \
    acc[ah][mfB][2] = MFMA(p10, b20, acc[ah][mfB][2]); \
    acc[ah][mfB][3] = MFMA(p10, b30, acc[ah][mfB][3]); \
    acc[ah][mfA][0] = MFMA(p01, b01, acc[ah][mfA][0]); \
    acc[ah][mfA][1] = MFMA(p01, b11, acc[ah][mfA][1]); \
    acc[ah][mfA][2] = MFMA(p01, b21, acc[ah][mfA][2]); \
    acc[ah][mfA][3] = MFMA(p01, b31, acc[ah][mfA][3]); \
    acc[ah][mfB][0] = MFMA(p11, b01, acc[ah][mfB][0]); \
    acc[ah][mfB][1] = MFMA(p11, b11, acc[ah][mfB][1]); \
    acc[ah][mfB][2] = MFMA(p11, b21, acc[ah][mfB][2]); \
    acc[ah][mfB][3] = MFMA(p11, b31, acc[ah][mfB][3]);

#define SGB0 __builtin_amdgcn_sched_barrier(0)
#define SBAR __builtin_amdgcn_s_barrier()

    // R12 schedule; gA1/gT2 guard the tail's dummy stages (wave-uniform:
    // all waves share t, so no divergence; skipped loads are never read and
    // counted vmcnt passes trivially with fewer outstanding).
#define GROUP(p, kbA1, kbT2, gA1, gT2) \
    { \
        /* phi1: consume B+A0a (serial head), prefetch A0b */ \
        bf16x8 b00 = LDB(p, 0, c0), b01 = LDB(p, 0, c1), b10 = LDB(p, 1, c0), b11 = LDB(p, 1, c1); \
        bf16x8 b20 = LDB(p, 2, c0), b21 = LDB(p, 2, c1), b30 = LDB(p, 3, c0), b31 = LDB(p, 3, c1); \
        bf16x8 a0 = LDA(p, 0, 0, c0), a1 = LDA(p, 0, 0, c1); \
        bf16x8 a2 = LDA(p, 0, 1, c0), a3 = LDA(p, 0, 1, c1); \
        bf16x8 n0 = LDA(p, 0, 2, c0), n1 = LDA(p, 0, 2, c1); \
        bf16x8 n2 = LDA(p, 0, 3, c0), n3 = LDA(p, 0, 3, c1); \
        asm volatile("s_waitcnt vmcnt(6)" ::: "memory"); \
        SGB0; \
        __builtin_amdgcn_s_setprio(1); \
        MF16(0, 0, 1, a0, a1, a2, a3) \
        __builtin_amdgcn_s_setprio(0); \
        if (gA1) STG_A((p) ^ 1, 1, kbA1); \
        SBAR; \
        /* phi2: prefetch A1a, compute A0b */ \
        a0 = LDA(p, 1, 0, c0); a1 = LDA(p, 1, 0, c1); \
        a2 = LDA(p, 1, 1, c0); a3 = LDA(p, 1, 1, c1); \
        asm volatile("s_waitcnt vmcnt(6)" ::: "memory"); \
        SGB0; \
        __builtin_amdgcn_s_setprio(1); \
        MF16(0, 2, 3, n0, n1, n2, n3) \
        __builtin_amdgcn_s_setprio(0); \
        if (gT2) STG_B(p, 0, kbT2); \
        SBAR; \
        /* phi3: prefetch A1b, compute A1a */ \
        n0 = LDA(p, 1, 2, c0); n1 = LDA(p, 1, 2, c1); \
        n2 = LDA(p, 1, 3, c0); n3 = LDA(p, 1, 3, c1); \
        asm volatile("s_waitcnt vmcnt(6)" ::: "memory"); \
        SGB0; \
        __builtin_amdgcn_s_setprio(1); \
        MF16(1, 0, 1, a0, a1, a2, a3) \
        __builtin_amdgcn_s_setprio(0); \
        if (gT2) STG_A(p, 0, kbT2); \
        SBAR; \
        /* phi4: pure MFMA on A1b */ \
        SGB0; \
        __builtin_amdgcn_s_setprio(1); \
        MF16(1, 2, 3, n0, n1, n2, n3) \
        __builtin_amdgcn_s_setprio(0); \
        if (gT2) STG_B(p, 1, kbT2); \
        SBAR; \
    }

    // ---- prologue: 7 half-tiles in steady-state virtual order
    STG_B(0, 0, 0);
    STG_A(0, 0, 0);
    STG_B(0, 1, 0);
    STG_A(0, 1, 0);
    STG_B(1, 0, 128);
    STG_A(1, 0, 128);
    STG_B(1, 1, 128);
    asm volatile("s_waitcnt vmcnt(6)" ::: "memory");
    __builtin_amdgcn_s_barrier();

    // ---- main loop: 15 full iterations + guarded tail (K = 2048 = 32 x 64)
    for (int it = 0; it < 15; ++it) {
        const int t0 = 2 * it;
        const size_t kA1_0 = (size_t)(t0 + 1) * 128;
        const size_t kT2_0 = (size_t)(t0 + 2) * 128;
        const size_t kA1_1 = kT2_0;
        const size_t kT2_1 = (size_t)(t0 + 3) * 128;
        GROUP(0, kA1_0, kT2_0, true, true)
        GROUP(1, kA1_1, kT2_1, true, true)
    }
    // it = 15: t0 = 30; A1(31) is real; tiles 32/33 do not exist -> skip.
    GROUP(0, (size_t)31 * 128, 0, true, false)
    GROUP(1, 0, 0, false, false)

    // ---- register-only fused LSTM epilogue ---------------------------------
    const int hl = lane & 15;
    const int er0 = (lane >> 4) * 4;
    const int myh = (int)(Ccol0 >> 2) + wn * 16 + hl;
    const f32x4 bs = *(const f32x4*)(bsum + (size_t)myh * 4);

    float cp[2][4][4];
#pragma unroll
    for (int ah = 0; ah < 2; ++ah)
#pragma unroll
        for (int mf = 0; mf < 4; ++mf)
#pragma unroll
            for (int r = 0; r < 4; ++r)
                cp[ah][mf][r] = cprev[(size_t)(Crow0 + ah * 128 + wm * 64 + mf * 16 + er0 + r) * 1024 + myh];

#pragma unroll
    for (int ah = 0; ah < 2; ++ah)
#pragma unroll
        for (int mf = 0; mf < 4; ++mf)
#pragma unroll
            for (int r = 0; r < 4; ++r) {
                float gi = acc[ah][mf][0][r] + bs[0];
                float gf = acc[ah][mf][1][r] + bs[1];
                float go = acc[ah][mf][2][r] + bs[2];
                float gz = acc[ah][mf][3][r] + bs[3];
                float iv = 1.f / (1.f + __expf(-gi));
                float fv = 1.f / (1.f + __expf(-gf));
                float ov = 1.f / (1.f + __expf(-go));
                float zv = fast_tanh(gz);
                float cc = fmaf(iv, zv, fv * cp[ah][mf][r]);
                float hv = ov * fast_tanh(cc);
                const size_t oidx =
                    (size_t)(Crow0 + ah * 128 + wm * 64 + mf * 16 + er0 + r) * 1024 + myh;
                out[oidx] = hv;
                out[(1 << 22) + oidx] = cc;
            }

    // drain any outstanding loads before LDS dealloc at endpgm
    asm volatile("s_waitcnt vmcnt(0)" ::: "memory");
}

// ---------------------------------------------------------------------------
extern "C" void kernel_launch(void* const* d_in, const int* in_sizes, int n_in,
                              void* d_out, int out_size, void* d_ws, size_t ws_size,
                              hipStream_t stream) {
    const float* x  = (const float*)d_in[0];
    const float* h  = (const float*)d_in[1];
    const float* c  = (const float*)d_in[2];
    const float* W  = (const float*)d_in[3];
    const float* bW = (const float*)d_in[4];
    const float* U  = (const float*)d_in[5];
    const float* bU = (const float*)d_in[6];
    float* out = (float*)d_out;

    char* ws = (char*)d_ws;
    unsigned short* Xc = (unsigned short*)ws;                         // 16 MB
    unsigned short* Wc = (unsigned short*)(ws + ((size_t)16 << 20));  // 16 MB
    float* bsum = (float*)(ws + ((size_t)32 << 20));                  // 16 KB

    (void)hipFuncSetAttribute((const void*)gemm_8ph,
                              hipFuncAttributeMaxDynamicSharedMemorySize, 131072);

    hipLaunchKernelGGL(pack_bf16, dim3(2048), dim3(256), 0, stream,
                       x, h, W, U, bW, bU, Xc, Wc, bsum);
    hipLaunchKernelGGL(gemm_8ph, dim3(256), dim3(512), 131072, stream,
                       Xc, Wc, bsum, c, out);
}

// Round 17
// 82.849 us; speedup vs baseline: 1.1639x; 1.0013x over previous
//
#include <hip/hip_runtime.h>
#include <math.h>

// Problem constants
#define Mm 4096   // batch B
#define Nn 4096   // 4*H, column map: c = (h>>4)*64 + g*16 + (h&15)
#define Kk 2048   // D + H

typedef __bf16 bf16x8 __attribute__((ext_vector_type(8)));
typedef float f32x4 __attribute__((ext_vector_type(4)));

__device__ __forceinline__ unsigned short f2bf(float f) {
    union { float f; unsigned u; } v; v.f = f;
    unsigned r = v.u + 0x7FFFu + ((v.u >> 16) & 1u);  // RNE
    return (unsigned short)(r >> 16);
}

__device__ __forceinline__ float fast_tanh(float x) {
    return 1.f - 2.f / (1.f + __expf(2.f * x));
}

// ---------------------------------------------------------------------------
// Kernel 1: pack x|h -> Xcat bf16 [4096][2048]
//   W|U -> Wcat bf16 [4096][2048], row n' = (h>>4)*64 + g*16 + (h&15)
//   bsum[4h+g] = bW+bU.
// ---------------------------------------------------------------------------
__global__ void pack_bf16(const float* __restrict__ x, const float* __restrict__ h,
                          const float* __restrict__ W, const float* __restrict__ U,
                          const float* __restrict__ bW, const float* __restrict__ bU,
                          unsigned short* __restrict__ Xc, unsigned short* __restrict__ Wc,
                          float* __restrict__ bsum) {
    if (blockIdx.x == 0) {
#pragma unroll
        for (int j = 0; j < 16; ++j) {
            int n = threadIdx.x * 16 + j;
            int hh = n >> 2, g = n & 3;
            bsum[n] = bW[g * 1024 + hh] + bU[g * 1024 + hh];
        }
    }
    const int PER = (4096 * 1024) / 4;
    for (int t = blockIdx.x * blockDim.x + threadIdx.x; t < 4 * PER;
         t += gridDim.x * blockDim.x) {
        int region = t >> 20;
        int i = t & (PER - 1);
        int row = i >> 8;
        int c4  = i & 255;
        const float* src = (region == 0) ? x : (region == 1) ? h : (region == 2) ? W : U;
        float4 v = reinterpret_cast<const float4*>(src)[i];
        ushort4 o;
        o.x = f2bf(v.x); o.y = f2bf(v.y); o.z = f2bf(v.z); o.w = f2bf(v.w);
        if (region < 2) {
            *reinterpret_cast<ushort4*>(Xc + (size_t)row * 2048 + (region << 10) + c4 * 4) = o;
        } else {
            int g = row >> 10, hh = row & 1023;
            int np = ((hh >> 4) << 6) + (g << 4) + (hh & 15);
            *reinterpret_cast<ushort4*>(Wc + (size_t)np * 2048 + ((region & 1) << 10) + c4 * 4) = o;
        }
    }
}

// ---------------------------------------------------------------------------
// Kernel 2: 256x256 GEMM, register-neutral full cross-phase pipeline
//           (dead-slot rotation), guarded tail, register-only LSTM epilogue.
// ---------------------------------------------------------------------------
__device__ __forceinline__ void gl16(const void* g, void* l) {
    __builtin_amdgcn_global_load_lds(
        (const __attribute__((address_space(1))) void*)g,
        (__attribute__((address_space(3))) void*)l, 16, 0, 0);
}

#define A_OFF(p, ah) (((p) * 2 + (ah)) * 16384)
#define B_OFF(p, hb) (65536 + ((p) * 2 + (hb)) * 16384)

__global__ __launch_bounds__(512, 2) void gemm_8ph(const unsigned short* __restrict__ A,
                                                   const unsigned short* __restrict__ Bw,
                                                   const float* __restrict__ bsum,
                                                   const float* __restrict__ cprev,
                                                   float* __restrict__ out) {
    extern __shared__ char lds[];
    const int tid = threadIdx.x, lane = tid & 63, wave = tid >> 6;
    const int wm = wave >> 2, wn = wave & 3;

    const int bid = blockIdx.x;
    const int swz = (bid & 7) * 32 + (bid >> 3);
    const int bm = swz & 15, bn = swz >> 4;
    const size_t Crow0 = (size_t)bm * 256, Ccol0 = (size_t)bn * 256;

    // ---- staging source addresses (inverse-swizzled global, linear LDS dest)
    const int srow = wave * 8 + (lane >> 3);
    const int scolswz = (((lane & 7) ^ (lane >> 3)) << 4);
    const char* aS[2][2];
    const char* bS[2][2];
#pragma unroll
    for (int ah = 0; ah < 2; ++ah)
#pragma unroll
        for (int j = 0; j < 2; ++j) {
            aS[ah][j] = (const char*)A  + (size_t)(Crow0 + ah * 128 + j * 64 + srow) * 4096 + scolswz;
            bS[ah][j] = (const char*)Bw + (size_t)(Ccol0 + ah * 128 + j * 64 + srow) * 4096 + scolswz;
        }

#define STG_A(p, ah, kb) do { \
        gl16(aS[ah][0] + (kb), lds + A_OFF(p, ah) + wave * 1024); \
        gl16(aS[ah][1] + (kb), lds + A_OFF(p, ah) + 8192 + wave * 1024); } while (0)
#define STG_B(p, hb, kb) do { \
        gl16(bS[hb][0] + (kb), lds + B_OFF(p, hb) + wave * 1024); \
        gl16(bS[hb][1] + (kb), lds + B_OFF(p, hb) + 8192 + wave * 1024); } while (0)

    // ---- LDS read addressing (swizzled), 16x16x32 frags
    const int arowB = (wm * 64 + (lane & 15)) * 128;
    const int browB = ((wn & 1) * 64 + (lane & 15)) * 128;
    const int c0 = (((lane >> 4) << 4)) ^ ((lane & 7) << 4);
    const int c1 = (64 + ((lane >> 4) << 4)) ^ ((lane & 7) << 4);
    const int bhb = wn >> 1;

#define LDA(p, ah, mfl, ck) (*(const bf16x8*)(lds + A_OFF(p, ah) + arowB + (mfl) * 2048 + (ck)))
#define LDB(p, nf, ck)      (*(const bf16x8*)(lds + B_OFF(p, bhb) + browB + (nf) * 2048 + (ck)))

    f32x4 acc[2][4][4] = {};
    // persistent operand registers (dead-slot rotation; no extra buffers)
    bf16x8 b00, b01, b10, b11, b20, b21, b30, b31;
    bf16x8 a0, a1, a2, a3, n0, n1, n2, n3;

#define MFMA(a, b, c) __builtin_amdgcn_mfma_f32_16x16x32_bf16(a, b, c, 0, 0, 0)
    // 16 MFMAs per cluster, acc reuse distance 8; per-acc order k0 then k1.
#define MF16(ah, mfA, mfB, p00, p01, p10, p11) \
    acc[ah][mfA][0] = MFMA(p00, b00, acc[ah][mfA][0]); \
    acc[ah][mfA][1] = MFMA(p00, b10, acc[ah][mfA][1]); \
    acc[ah][mfA][2] = MFMA(p00, b20, acc[ah][mfA][2]); \
    acc[ah][mfA][3] = MFMA(p00, b30, acc[ah][mfA][3]); \
    acc[ah][mfB][0] = MFMA(p10, b00, acc[ah][mfB][0]); \
    acc[ah][mfB][1] = MFMA(p10, b10, acc[ah][mfB][1]); \
    acc[ah][mfB][2] = MFMA(p10, b20, acc[ah][mfB][2]); \
    acc[ah][mfB][3] = MFMA(p10, b30, acc[ah][mfB][3]); \
    acc[ah][mfA][0] = MFMA(p01, b01, acc[ah][mfA][0]); \
    acc[ah][mfA][1] = MFMA(p01, b11, acc[ah][mfA][1]); \
    acc[ah][mfA][2] = MFMA(p01, b21, acc[ah][mfA][2]); \
    acc[ah][mfA][3] = MFMA(p01, b31, acc[ah][mfA][3]); \
    acc[ah][mfB][0] = MFMA(p11, b01, acc[ah][mfB][0]); \
    acc[ah][mfB][1] = MFMA(p11, b11, acc[ah][mfB][1]); \
    acc[ah][mfB][2] = MFMA(p11, b21, acc[ah][mfB][2]); \
    acc[ah][mfB][3] = MFMA(p11, b31, acc[ah][mfB][3]);

#define SGB0 __builtin_amdgcn_sched_barrier(0)
#define SBAR __builtin_amdgcn_s_barrier()

    // Full pipeline, register-neutral. Per phase the just-died operand slot
    // is refilled with next-phase/next-tile operands:
    //  phi1: cluster(a=A0a(t), b=B(t));   head loads A0b(t)->n
    //  phi2: cluster(n=A0b(t));           head loads A1a(t)->a
    //  phi3: cluster(a=A1a(t));           head loads A1b(t)->n
    //  phi4: cluster(n=A1b(t));           head loads A0a(t+1)->a,
    //        tail (after cluster, WAR on b) loads B(t+1)->b
    // Drain ledger (stages B0@phi2,A0@phi3,B1@phi4,A1@phi1; vmcnt(6)@phi1-3):
    //  A0(t+1),B0(t+1) drain @phi2(t); B1(t+1),A1(t+1) drain @phi3(t) ->
    //  phi4's reads of A0a(t+1)/B(t+1) are drained >=1 barrier earlier.
    //  Slot-WAR: each STG is >=1 barrier after the cluster-lgkm-wait that
    //  completes the slot's last reads (all 4 edges checked).
#define GROUP(p, kbA1, kbT2, gA1, gT2) \
    { \
        /* phi1 */ \
        n0 = LDA(p, 0, 2, c0); n1 = LDA(p, 0, 2, c1); \
        n2 = LDA(p, 0, 3, c0); n3 = LDA(p, 0, 3, c1); \
        asm volatile("s_waitcnt vmcnt(6)" ::: "memory"); \
        SGB0; \
        __builtin_amdgcn_s_setprio(1); \
        MF16(0, 0, 1, a0, a1, a2, a3) \
        __builtin_amdgcn_s_setprio(0); \
        if (gA1) STG_A((p) ^ 1, 1, kbA1); \
        SBAR; \
        /* phi2 */ \
        a0 = LDA(p, 1, 0, c0); a1 = LDA(p, 1, 0, c1); \
        a2 = LDA(p, 1, 1, c0); a3 = LDA(p, 1, 1, c1); \
        asm volatile("s_waitcnt vmcnt(6)" ::: "memory"); \
        SGB0; \
        __builtin_amdgcn_s_setprio(1); \
        MF16(0, 2, 3, n0, n1, n2, n3) \
        __builtin_amdgcn_s_setprio(0); \
        if (gT2) STG_B(p, 0, kbT2); \
        SBAR; \
        /* phi3 */ \
        n0 = LDA(p, 1, 2, c0); n1 = LDA(p, 1, 2, c1); \
        n2 = LDA(p, 1, 3, c0); n3 = LDA(p, 1, 3, c1); \
        asm volatile("s_waitcnt vmcnt(6)" ::: "memory"); \
        SGB0; \
        __builtin_amdgcn_s_setprio(1); \
        MF16(1, 0, 1, a0, a1, a2, a3) \
        __builtin_amdgcn_s_setprio(0); \
        if (gT2) STG_A(p, 0, kbT2); \
        SBAR; \
        /* phi4 */ \
        a0 = LDA((p) ^ 1, 0, 0, c0); a1 = LDA((p) ^ 1, 0, 0, c1); \
        a2 = LDA((p) ^ 1, 0, 1, c0); a3 = LDA((p) ^ 1, 0, 1, c1); \
        SGB0; \
        __builtin_amdgcn_s_setprio(1); \
        MF16(1, 2, 3, n0, n1, n2, n3) \
        __builtin_amdgcn_s_setprio(0); \
        b00 = LDB((p) ^ 1, 0, c0); b01 = LDB((p) ^ 1, 0, c1); \
        b10 = LDB((p) ^ 1, 1, c0); b11 = LDB((p) ^ 1, 1, c1); \
        b20 = LDB((p) ^ 1, 2, c0); b21 = LDB((p) ^ 1, 2, c1); \
        b30 = LDB((p) ^ 1, 3, c0); b31 = LDB((p) ^ 1, 3, c1); \
        if (gT2) STG_B(p, 1, kbT2); \
        SBAR; \
    }

    // ---- prologue: 7 half-tiles in steady-state virtual order
    STG_B(0, 0, 0);
    STG_A(0, 0, 0);
    STG_B(0, 1, 0);
    STG_A(0, 1, 0);
    STG_B(1, 0, 128);
    STG_A(1, 0, 128);
    STG_B(1, 1, 128);
    asm volatile("s_waitcnt vmcnt(6)" ::: "memory");   // drains through A1(0)
    __builtin_amdgcn_s_barrier();
    // prime b = B(0), a = A0a(0)  (both drained above)
    b00 = LDB(0, 0, c0); b01 = LDB(0, 0, c1);
    b10 = LDB(0, 1, c0); b11 = LDB(0, 1, c1);
    b20 = LDB(0, 2, c0); b21 = LDB(0, 2, c1);
    b30 = LDB(0, 3, c0); b31 = LDB(0, 3, c1);
    a0 = LDA(0, 0, 0, c0); a1 = LDA(0, 0, 0, c1);
    a2 = LDA(0, 0, 1, c0); a3 = LDA(0, 0, 1, c1);

    // ---- main loop: 15 full iterations + guarded tail (K = 2048 = 32 x 64)
    for (int it = 0; it < 15; ++it) {
        const int t0 = 2 * it;
        const size_t kA1_0 = (size_t)(t0 + 1) * 128;
        const size_t kT2_0 = (size_t)(t0 + 2) * 128;
        const size_t kA1_1 = kT2_0;
        const size_t kT2_1 = (size_t)(t0 + 3) * 128;
        GROUP(0, kA1_0, kT2_0, true, true)
        GROUP(1, kA1_1, kT2_1, true, true)
    }
    // it = 15: t0 = 30; A1(31) real; tiles 32/33 don't exist -> skip stages.
    // Tail phi4 reg-loads read stale LDS into never-consumed regs (safe).
    GROUP(0, (size_t)31 * 128, 0, true, false)
    GROUP(1, 0, 0, false, false)

    // ---- register-only fused LSTM epilogue ---------------------------------
    const int hl = lane & 15;
    const int er0 = (lane >> 4) * 4;
    const int myh = (int)(Ccol0 >> 2) + wn * 16 + hl;
    const f32x4 bs = *(const f32x4*)(bsum + (size_t)myh * 4);

    float cp[2][4][4];
#pragma unroll
    for (int ah = 0; ah < 2; ++ah)
#pragma unroll
        for (int mf = 0; mf < 4; ++mf)
#pragma unroll
            for (int r = 0; r < 4; ++r)
                cp[ah][mf][r] = cprev[(size_t)(Crow0 + ah * 128 + wm * 64 + mf * 16 + er0 + r) * 1024 + myh];

#pragma unroll
    for (int ah = 0; ah < 2; ++ah)
#pragma unroll
        for (int mf = 0; mf < 4; ++mf)
#pragma unroll
            for (int r = 0; r < 4; ++r) {
                float gi = acc[ah][mf][0][r] + bs[0];
                float gf = acc[ah][mf][1][r] + bs[1];
                float go = acc[ah][mf][2][r] + bs[2];
                float gz = acc[ah][mf][3][r] + bs[3];
                float iv = 1.f / (1.f + __expf(-gi));
                float fv = 1.f / (1.f + __expf(-gf));
                float ov = 1.f / (1.f + __expf(-go));
                float zv = fast_tanh(gz);
                float cc = fmaf(iv, zv, fv * cp[ah][mf][r]);
                float hv = ov * fast_tanh(cc);
                const size_t oidx =
                    (size_t)(Crow0 + ah * 128 + wm * 64 + mf * 16 + er0 + r) * 1024 + myh;
                out[oidx] = hv;
                out[(1 << 22) + oidx] = cc;
            }

    // drain any outstanding loads before LDS dealloc at endpgm
    asm volatile("s_waitcnt vmcnt(0)" ::: "memory");
}

// ---------------------------------------------------------------------------
extern "C" void kernel_launch(void* const* d_in, const int* in_sizes, int n_in,
                              void* d_out, int out_size, void* d_ws, size_t ws_size,
                              hipStream_t stream) {
    const float* x  = (const float*)d_in[0];
    const float* h  = (const float*)d_in[1];
    const float* c  = (const float*)d_in[2];
    const float* W  = (const float*)d_in[3];
    const float* bW = (const float*)d_in[4];
    const float* U  = (const float*)d_in[5];
    const float* bU = (const float*)d_in[6];
    float* out = (float*)d_out;

    char* ws = (char*)d_ws;
    unsigned short* Xc = (unsigned short*)ws;                         // 16 MB
    unsigned short* Wc = (unsigned short*)(ws + ((size_t)16 << 20));  // 16 MB
    float* bsum = (float*)(ws + ((size_t)32 << 20));                  // 16 KB

    (void)hipFuncSetAttribute((const void*)gemm_8ph,
                              hipFuncAttributeMaxDynamicSharedMemorySize, 131072);

    hipLaunchKernelGGL(pack_bf16, dim3(2048), dim3(256), 0, stream,
                       x, h, W, U, bW, bU, Xc, Wc, bsum);
    hipLaunchKernelGGL(gemm_8ph, dim3(256), dim3(512), 131072, stream,
                       Xc, Wc, bsum, c, out);
}